// Round 21
// baseline (67.868 us; speedup 1.0000x reference)
//
#include <hip/hip_runtime.h>

#define NFEAT   100000
#define NBATCH  256
#define DIM     128
#define MARGIN_F 0.5f
#define FLT_BIG 3.402823466e+38f

// ---- main geometry: 625 blocks x 160 feature rows = 100000 exactly
#define NCHUNK  625
#define CROWS   160
#define NTILE   10                 // 16-row B-tiles per block
#define GRID    NCHUNK

// ---- f32 fallback geometry (R13): 1250 x 80
#define GRIDF   1250
#define RPBF    80
#define NTILEF  5

typedef __bf16 bf8_t  __attribute__((ext_vector_type(8)));
typedef short  sh8_t  __attribute__((ext_vector_type(8)));
typedef float  f32x4  __attribute__((ext_vector_type(4)));

__device__ __forceinline__ bf8_t pack8(float4 v0, float4 v1) {
  bf8_t r;
  r[0] = (__bf16)v0.x; r[1] = (__bf16)v0.y; r[2] = (__bf16)v0.z; r[3] = (__bf16)v0.w;
  r[4] = (__bf16)v1.x; r[5] = (__bf16)v1.y; r[6] = (__bf16)v1.z; r[7] = (__bf16)v1.w;
  return r;
}

template <typename VA, typename VC>
__device__ __forceinline__ auto mfma_sel(VA a, VA b, VC c, int)
    -> decltype(__builtin_amdgcn_mfma_f32_16x16x32_bf16(a, b, c, 0, 0, 0)) {
  return __builtin_amdgcn_mfma_f32_16x16x32_bf16(a, b, c, 0, 0, 0);
}
template <typename VA, typename VC>
__device__ __forceinline__ VC mfma_sel(VA a, VA b, VC c, long) {
  return __builtin_amdgcn_mfma_f32_16x16x32_bf16(
      __builtin_bit_cast(sh8_t, a), __builtin_bit_cast(sh8_t, b), c, 0, 0, 0);
}
__device__ __forceinline__ f32x4 mfma_bf16(bf8_t a, bf8_t b, f32x4 c) {
  return mfma_sel(a, b, c, 0);
}

#if defined(__has_builtin)
#if __has_builtin(__builtin_amdgcn_global_load_lds)
#define HAVE_GLLDS 1
#endif
#endif

__device__ __forceinline__ void stage16(const char* g, char* l) {
#ifdef HAVE_GLLDS
  __builtin_amdgcn_global_load_lds(
      (const __attribute__((address_space(1))) unsigned int*)g,
      (__attribute__((address_space(3))) unsigned int*)l, 16, 0, 0);
#else
  *reinterpret_cast<float4*>(l) = *reinterpret_cast<const float4*>(g);
#endif
}

// ============================================================================
// K1a: streaming f32->bf16 cast of inputs (64 KB) + features (25.6 MB) into
// d_ws. Measured R16-20: ~8us (~9 TB/s).
// ============================================================================
#define NG_IN   (NBATCH * DIM / 8)
#define NG_ALL  (NG_IN + NFEAT * DIM / 8)
__global__ __launch_bounds__(256) void cast_bf16(
    const float* __restrict__ inputs, const float* __restrict__ features,
    __bf16* __restrict__ inb, __bf16* __restrict__ featb,
    float* __restrict__ out)
{
  if (blockIdx.x == 0 && threadIdx.x == 0) out[0] = 0.0f;  // K2 accumulates
  const int gid    = blockIdx.x * 256 + threadIdx.x;
  const int stride = gridDim.x * 256;
  for (int i = gid; i < NG_ALL; i += stride) {
    const float* src; __bf16* dst;
    if (i < NG_IN) { src = inputs + (size_t)i * 8;             dst = inb   + (size_t)i * 8; }
    else           { src = features + (size_t)(i - NG_IN) * 8; dst = featb + (size_t)(i - NG_IN) * 8; }
    float4 v0 = *reinterpret_cast<const float4*>(src);
    float4 v1 = *reinterpret_cast<const float4*>(src + 4);
    *reinterpret_cast<bf8_t*>(dst) = pack8(v0, v1);
  }
}

// ============================================================================
// K1b (R21): independent-wave MFMA streamer, PINNED prefetch, SIZED TO THE
// REAL REGISTER BUDGET. R20 revealed the allocator grants MFMA kernels at
// most 128 arch VGPRs regardless of launch bounds (unified-file AGPR split);
// R20's 4-M-tile design (demand ~150) spilled 22.5 MB of scratch. This
// design's demand: afrag 32 + pinned bA/bB 18 + minmax 16 + meta 8 +
// addressing ~14 = ~88 regs -- fits under 128 with headroom, so the PIN
// (asm "+v", defeats R3/R10/R19 load-sinking) cannot cause spills.
// 625 blocks x 512 thr (8 waves x 2 M-tiles = all 256 batch rows; featb
// read exactly once, no XCD-sibling double-fetch). Zero LDS, zero barriers,
// ~20 independent waves/CU (the only measured-fast shape, K1a's regime).
// Partials [chunk][row] contiguous (R13: transposed = cross-XCD ping-pong).
// MFMA 16x16x32 layouts (guide §3, m89/m91-verified):
//   A: lane l holds A[m0 + (l&15)][ks*32 + (l>>4)*8 + e]
//   B: lane l holds B[ks*32 + (l>>4)*8 + e][j0 + (l&15)]  (= featb[j][k])
//   D: lane l reg r = sim[m0 + (l>>4)*4 + r][j0 + (l&15)]
// ============================================================================
__global__ __launch_bounds__(512, 2) void triplet_main(
    const __bf16* __restrict__ inb, const __bf16* __restrict__ featb,
    const int* __restrict__ targets, const int* __restrict__ flabels,
    const int* __restrict__ idx,
    float* __restrict__ ppos, float* __restrict__ pneg)
{
  const int tid   = threadIdx.x;
  const int lane  = tid & 63;
  const int wv    = tid >> 6;       // 0..7: wave owns batch rows [32wv,32wv+32)
  const int l15   = lane & 15;
  const int lg    = lane >> 4;      // 0..3
  const int chunk = blockIdx.x;     // 0..624
  const int m0    = wv * 32;
  const int frow0 = chunk * CROWS;  // first of 160 feature rows

  // ---- A fragments: direct bf16, once per wave (2 M-tiles, 32 VGPRs)
  bf8_t afrag[2][4];
#pragma unroll
  for (int mt = 0; mt < 2; ++mt) {
    const char* abase = (const char*)inb + (size_t)(m0 + mt * 16 + l15) * 256 + lg * 16;
#pragma unroll
    for (int ks = 0; ks < 4; ++ks)
      afrag[mt][ks] = *reinterpret_cast<const bf8_t*>(abase + ks * 64);
  }

  // packed row metadata: meta = (self_gallery_row << 10) | target (lab<1024)
  int meta[2][4];
#pragma unroll
  for (int mt = 0; mt < 2; ++mt)
#pragma unroll
    for (int rr = 0; rr < 4; ++rr) {
      const int row = m0 + mt * 16 + lg * 4 + rr;
      meta[mt][rr] = (idx[row] << 10) | targets[row];
    }

  float minpos[2][4], maxneg[2][4];
#pragma unroll
  for (int mt = 0; mt < 2; ++mt)
#pragma unroll
    for (int rr = 0; rr < 4; ++rr) { minpos[mt][rr] = FLT_BIG; maxneg[mt][rr] = -FLT_BIG; }

  // ---- B stream: lane reads featb[frow0 + t*16 + l15][ks*32 + lg*8 ..+8]
  const char* bbase = (const char*)featb + ((size_t)frow0 + l15) * 256 + lg * 16;
  const int*  lbase = flabels + frow0 + l15;

#define LOADB(buf, labv, t)                                        \
  do {                                                             \
    const char* p_ = bbase + (size_t)(t) * 4096;                   \
    buf[0] = *reinterpret_cast<const bf8_t*>(p_);                  \
    buf[1] = *reinterpret_cast<const bf8_t*>(p_ + 64);             \
    buf[2] = *reinterpret_cast<const bf8_t*>(p_ + 128);            \
    buf[3] = *reinterpret_cast<const bf8_t*>(p_ + 192);            \
    labv = lbase[(t) * 16];                                        \
  } while (0)

  // PIN: values must be live-in-registers HERE -- sinking impossible (R19),
  // and at ~88-reg total demand the pin cannot force spills (R20's failure).
#define PIN(buf, labv)                                             \
  asm volatile("" : "+v"(buf[0]), "+v"(buf[1]), "+v"(buf[2]),      \
                    "+v"(buf[3]), "+v"(labv))

#define TILE_COMPUTE(buf, labj, t)                                 \
  do {                                                             \
    f32x4 acc0 = {0.f, 0.f, 0.f, 0.f};                             \
    f32x4 acc1 = {0.f, 0.f, 0.f, 0.f};                             \
    _Pragma("unroll")                                              \
    for (int ks = 0; ks < 4; ++ks) {                               \
      acc0 = mfma_bf16(afrag[0][ks], buf[ks], acc0);               \
      acc1 = mfma_bf16(afrag[1][ks], buf[ks], acc1);               \
    }                                                              \
    const int j_ = frow0 + (t) * 16 + l15;                         \
    _Pragma("unroll")                                              \
    for (int rr = 0; rr < 4; ++rr) {                               \
      {                                                            \
        const int  m_   = meta[0][rr];                             \
        const bool same = ((labj) == (m_ & 1023));                 \
        const bool self = (j_ == (m_ >> 10));                      \
        minpos[0][rr] = fminf(minpos[0][rr],                       \
                              (same && !self) ? acc0[rr] : FLT_BIG); \
        maxneg[0][rr] = fmaxf(maxneg[0][rr],                       \
                              same ? -FLT_BIG : acc0[rr]);         \
      }                                                            \
      {                                                            \
        const int  m_   = meta[1][rr];                             \
        const bool same = ((labj) == (m_ & 1023));                 \
        const bool self = (j_ == (m_ >> 10));                      \
        minpos[1][rr] = fminf(minpos[1][rr],                       \
                              (same && !self) ? acc1[rr] : FLT_BIG); \
        maxneg[1][rr] = fmaxf(maxneg[1][rr],                       \
                              same ? -FLT_BIG : acc1[rr]);         \
      }                                                            \
    }                                                              \
  } while (0)

  // depth-2 named-buffer prefetch, pinned
  bf8_t bA[4], bB[4];
  int   labA, labB;
  LOADB(bA, labA, 0); PIN(bA, labA);
  LOADB(bB, labB, 1); PIN(bB, labB);

#pragma unroll
  for (int t = 0; t < NTILE; t += 2) {
    {
      const int labj = labA;
      TILE_COMPUTE(bA, labj, t);
      if (t + 2 < NTILE) { LOADB(bA, labA, t + 2); PIN(bA, labA); }
    }
    {
      const int labj = labB;
      TILE_COMPUTE(bB, labj, t + 1);
      if (t + 3 < NTILE) { LOADB(bB, labB, t + 3); PIN(bB, labB); }
    }
  }
#undef LOADB
#undef PIN
#undef TILE_COMPUTE

  // ---- reduce across the 16-lane col group; contiguous [chunk][row] write
#pragma unroll
  for (int mt = 0; mt < 2; ++mt)
#pragma unroll
    for (int rr = 0; rr < 4; ++rr) {
      float mp = minpos[mt][rr], mn = maxneg[mt][rr];
#pragma unroll
      for (int m = 1; m < 16; m <<= 1) {
        mp = fminf(mp, __shfl_xor(mp, m, 64));
        mn = fmaxf(mn, __shfl_xor(mn, m, 64));
      }
      if (l15 == 0) {
        const int row = m0 + mt * 16 + lg * 4 + rr;
        ppos[chunk * NBATCH + row] = mp;
        pneg[chunk * NBATCH + row] = mn;
      }
    }
}

// ============================================================================
// Fallback (ws too small): R13 f32 monolith, known-good ~43us path.
// ============================================================================
__global__ __launch_bounds__(512, 2) void triplet_partial_f32(
    const float* __restrict__ inputs, const float* __restrict__ features,
    const int* __restrict__ targets, const int* __restrict__ flabels,
    const int* __restrict__ idx,
    float* __restrict__ ppos, float* __restrict__ pneg,
    float* __restrict__ out)
{
  __shared__ char sB[RPBF * DIM * 4];

  const int tid  = threadIdx.x;
  const int lane = tid & 63;
  const int wv   = tid >> 6;
  const int l15  = lane & 15;
  const int lg   = lane >> 4;
  const int m0   = wv * 32;
  const int blk  = blockIdx.x;
  const int rowbase = blk * RPBF;

  if (blk == 0 && tid == 0) out[0] = 0.0f;

#pragma unroll
  for (int i = 0; i < NTILEF; ++i) {
    const int p    = i * 8192 + tid * 16;
    const int prow = p >> 9;
    const int scol = (p & 511) ^ ((prow & 7) << 4);
    stage16((const char*)features + (size_t)(rowbase + prow) * 512 + scol, &sB[p]);
  }

  bf8_t afrag[2][4];
#pragma unroll
  for (int mt = 0; mt < 2; ++mt) {
    const float* ap = inputs + (m0 + mt * 16 + l15) * DIM;
    float4 v0[4], v1[4];
#pragma unroll
    for (int ks = 0; ks < 4; ++ks) {
      const int k = ks * 32 + lg * 8;
      v0[ks] = *reinterpret_cast<const float4*>(ap + k);
      v1[ks] = *reinterpret_cast<const float4*>(ap + k + 4);
    }
#pragma unroll
    for (int ks = 0; ks < 4; ++ks)
      afrag[mt][ks] = pack8(v0[ks], v1[ks]);
  }

  int lab[NTILEF];
#pragma unroll
  for (int t = 0; t < NTILEF; ++t)
    lab[t] = flabels[rowbase + t * 16 + l15];

  int meta[2][4];
#pragma unroll
  for (int mt = 0; mt < 2; ++mt)
#pragma unroll
    for (int rr = 0; rr < 4; ++rr) {
      const int row = m0 + mt * 16 + lg * 4 + rr;
      meta[mt][rr] = (idx[row] << 10) | targets[row];
    }

  float minpos[2][4], maxneg[2][4];
#pragma unroll
  for (int mt = 0; mt < 2; ++mt)
#pragma unroll
    for (int rr = 0; rr < 4; ++rr) { minpos[mt][rr] = FLT_BIG; maxneg[mt][rr] = -FLT_BIG; }

  __syncthreads();

  const int swz = (l15 & 7) << 4;
#pragma unroll
  for (int t = 0; t < NTILEF; ++t) {
    const char* rbase = &sB[(t * 16 + l15) * 512];
    const int   j     = rowbase + t * 16 + l15;
    const int   labj  = lab[t];

    f32x4 acc0 = {0.f, 0.f, 0.f, 0.f};
    f32x4 acc1 = {0.f, 0.f, 0.f, 0.f};
#pragma unroll
    for (int ks = 0; ks < 4; ++ks) {
      const int o = ks * 128 + lg * 32;
      float4 v0 = *reinterpret_cast<const float4*>(rbase + ((o)      ^ swz));
      float4 v1 = *reinterpret_cast<const float4*>(rbase + ((o + 16) ^ swz));
      bf8_t bf = pack8(v0, v1);
      acc0 = mfma_bf16(afrag[0][ks], bf, acc0);
      acc1 = mfma_bf16(afrag[1][ks], bf, acc1);
    }
#pragma unroll
    for (int rr = 0; rr < 4; ++rr) {
      {
        const int  m = meta[0][rr];
        const bool same = (labj == (m & 1023));
        const bool self = (j == (m >> 10));
        minpos[0][rr] = fminf(minpos[0][rr], (same && !self) ? acc0[rr] : FLT_BIG);
        maxneg[0][rr] = fmaxf(maxneg[0][rr], same ? -FLT_BIG : acc0[rr]);
      }
      {
        const int  m = meta[1][rr];
        const bool same = (labj == (m & 1023));
        const bool self = (j == (m >> 10));
        minpos[1][rr] = fminf(minpos[1][rr], (same && !self) ? acc1[rr] : FLT_BIG);
        maxneg[1][rr] = fmaxf(maxneg[1][rr], same ? -FLT_BIG : acc1[rr]);
      }
    }
  }

#pragma unroll
  for (int mt = 0; mt < 2; ++mt)
#pragma unroll
    for (int rr = 0; rr < 4; ++rr) {
      float mp = minpos[mt][rr], mn = maxneg[mt][rr];
#pragma unroll
      for (int m = 1; m < 16; m <<= 1) {
        mp = fminf(mp, __shfl_xor(mp, m, 64));
        mn = fmaxf(mn, __shfl_xor(mn, m, 64));
      }
      if (l15 == 0) {
        const int row = m0 + mt * 16 + lg * 4 + rr;
        ppos[blk * NBATCH + row] = mp;
        pneg[blk * NBATCH + row] = mn;
      }
    }
}

// Kernel 2: one block per batch row; fold nblk partials, hinge, atomic mean.
__global__ __launch_bounds__(256) void triplet_reduce(
    const float* __restrict__ ppos, const float* __restrict__ pneg,
    float* __restrict__ out, int nblk)
{
  const int r = blockIdx.x;
  const int t = threadIdx.x;
  float mp = FLT_BIG, mn = -FLT_BIG;
  for (int b = t; b < nblk; b += 256) {
    mp = fminf(mp, ppos[b * NBATCH + r]);
    mn = fmaxf(mn, pneg[b * NBATCH + r]);
  }
#pragma unroll
  for (int m = 1; m < 64; m <<= 1) {
    mp = fminf(mp, __shfl_xor(mp, m, 64));
    mn = fmaxf(mn, __shfl_xor(mn, m, 64));
  }
  __shared__ float smp[4], smn[4];
  if ((t & 63) == 0) { smp[t >> 6] = mp; smn[t >> 6] = mn; }
  __syncthreads();
  if (t == 0) {
    mp = fminf(fminf(smp[0], smp[1]), fminf(smp[2], smp[3]));
    mn = fmaxf(fmaxf(smn[0], smn[1]), fmaxf(smn[2], smn[3]));
    float loss = mn - mp + MARGIN_F;
    loss = loss > 0.f ? loss : 0.f;
    atomicAdd(out, loss * (1.0f / NBATCH));
  }
}

extern "C" void kernel_launch(void* const* d_in, const int* in_sizes, int n_in,
                              void* d_out, int out_size, void* d_ws, size_t ws_size,
                              hipStream_t stream) {
  const float* inputs   = (const float*)d_in[0];
  const float* features = (const float*)d_in[1];
  const int*   targets  = (const int*)d_in[2];
  const int*   flabels  = (const int*)d_in[3];
  const int*   idx      = (const int*)d_in[4];
  float* out = (float*)d_out;

  const size_t featb_bytes = (size_t)NFEAT * DIM * 2;      // 25.6 MB
  const size_t inb_bytes   = (size_t)NBATCH * DIM * 2;     // 64 KB
  const size_t part_bytes  = (size_t)NCHUNK * NBATCH * 4;  // 640 KB each

  if (ws_size >= featb_bytes + inb_bytes + 2 * part_bytes) {
    __bf16* featb = (__bf16*)d_ws;
    __bf16* inb   = (__bf16*)((char*)d_ws + featb_bytes);
    float*  ppos  = (float*)((char*)d_ws + featb_bytes + inb_bytes);
    float*  pneg  = ppos + (size_t)NCHUNK * NBATCH;
    cast_bf16<<<2048, 256, 0, stream>>>(inputs, features, inb, featb, out);
    triplet_main<<<GRID, 512, 0, stream>>>(inb, featb, targets, flabels, idx, ppos, pneg);
    triplet_reduce<<<NBATCH, 256, 0, stream>>>(ppos, pneg, out, NCHUNK);
  } else {
    float* ppos = (float*)d_ws;                       // [GRIDF][256]
    float* pneg = ppos + (size_t)GRIDF * NBATCH;      // ~2.56 MB total
    triplet_partial_f32<<<GRIDF, 512, 0, stream>>>(inputs, features, targets,
                                                   flabels, idx, ppos, pneg, out);
    triplet_reduce<<<NBATCH, 256, 0, stream>>>(ppos, pneg, out, GRIDF);
  }
}

// Round 22
// 67.814 us; speedup vs baseline: 1.0008x; 1.0008x over previous
//
#include <hip/hip_runtime.h>

#define NFEAT   100000
#define NBATCH  256
#define DIM     128
#define MARGIN_F 0.5f
#define FLT_BIG 3.402823466e+38f

// ---- main geometry: 625 blocks x 160 feature rows = 100000 exactly
#define NCHUNK  625
#define CROWS   160
#define NTILE   10                 // 16-row B-tiles per block
#define GRID    NCHUNK

// ---- f32 fallback geometry (R13): 1250 x 80
#define GRIDF   1250
#define RPBF    80
#define NTILEF  5

typedef __bf16 bf8_t  __attribute__((ext_vector_type(8)));
typedef short  sh8_t  __attribute__((ext_vector_type(8)));
typedef float  f32x4  __attribute__((ext_vector_type(4)));

__device__ __forceinline__ bf8_t pack8(float4 v0, float4 v1) {
  bf8_t r;
  r[0] = (__bf16)v0.x; r[1] = (__bf16)v0.y; r[2] = (__bf16)v0.z; r[3] = (__bf16)v0.w;
  r[4] = (__bf16)v1.x; r[5] = (__bf16)v1.y; r[6] = (__bf16)v1.z; r[7] = (__bf16)v1.w;
  return r;
}

template <typename VA, typename VC>
__device__ __forceinline__ auto mfma_sel(VA a, VA b, VC c, int)
    -> decltype(__builtin_amdgcn_mfma_f32_16x16x32_bf16(a, b, c, 0, 0, 0)) {
  return __builtin_amdgcn_mfma_f32_16x16x32_bf16(a, b, c, 0, 0, 0);
}
template <typename VA, typename VC>
__device__ __forceinline__ VC mfma_sel(VA a, VA b, VC c, long) {
  return __builtin_amdgcn_mfma_f32_16x16x32_bf16(
      __builtin_bit_cast(sh8_t, a), __builtin_bit_cast(sh8_t, b), c, 0, 0, 0);
}
__device__ __forceinline__ f32x4 mfma_bf16(bf8_t a, bf8_t b, f32x4 c) {
  return mfma_sel(a, b, c, 0);
}

#if defined(__has_builtin)
#if __has_builtin(__builtin_amdgcn_global_load_lds)
#define HAVE_GLLDS 1
#endif
#endif

__device__ __forceinline__ void stage16(const char* g, char* l) {
#ifdef HAVE_GLLDS
  __builtin_amdgcn_global_load_lds(
      (const __attribute__((address_space(1))) unsigned int*)g,
      (__attribute__((address_space(3))) unsigned int*)l, 16, 0, 0);
#else
  *reinterpret_cast<float4*>(l) = *reinterpret_cast<const float4*>(g);
#endif
}

// ============================================================================
// K1a: streaming f32->bf16 cast of inputs (64 KB) + features (25.6 MB) into
// d_ws. Measured R16-21: ~8us (~9 TB/s).
// ============================================================================
#define NG_IN   (NBATCH * DIM / 8)
#define NG_ALL  (NG_IN + NFEAT * DIM / 8)
__global__ __launch_bounds__(256) void cast_bf16(
    const float* __restrict__ inputs, const float* __restrict__ features,
    __bf16* __restrict__ inb, __bf16* __restrict__ featb,
    float* __restrict__ out)
{
  if (blockIdx.x == 0 && threadIdx.x == 0) out[0] = 0.0f;  // K2 accumulates
  const int gid    = blockIdx.x * 256 + threadIdx.x;
  const int stride = gridDim.x * 256;
  for (int i = gid; i < NG_ALL; i += stride) {
    const float* src; __bf16* dst;
    if (i < NG_IN) { src = inputs + (size_t)i * 8;             dst = inb   + (size_t)i * 8; }
    else           { src = features + (size_t)(i - NG_IN) * 8; dst = featb + (size_t)(i - NG_IN) * 8; }
    float4 v0 = *reinterpret_cast<const float4*>(src);
    float4 v1 = *reinterpret_cast<const float4*>(src + 4);
    *reinterpret_cast<bf8_t*>(dst) = pack8(v0, v1);
  }
}

// ============================================================================
// K1b (R22): HAND-PIPELINED loads -- volatile asm global_load + counted vmcnt.
// R21 post-mortem: the asm "+v" PIN *reads* the loaded values, so the
// compiler inserted s_waitcnt vmcnt(0) AT THE PIN -- the prefetch was
// synchronous. Across R1-R21 the prefetch never survived compilation
// (sinking R3/R10/R19, spills R5/R20, DMA drains R4-R8, barrier lockstep
// R18, value-pin waits R20/R21) -- always the same ~5000cyc/tile constant.
// This round removes the compiler from the schedule entirely (AITER/HK
// pattern, guide #5.5 T4):
//   - B-tile + label loads are VOLATILE INLINE ASM (saddr + 32-bit voffset):
//     cannot be sunk, reordered, or folded; no implicit waits exist.
//   - consumption gated by counted "s_waitcnt vmcnt(5)" (one tile's 5 loads
//     outstanding; NEVER 0 mid-loop) + sched_barrier(0) so MFMAs can't hoist
//     above the wait (guide rule 18).
//   - prologue drains normal loads (vmcnt(0)) between sched_barriers so the
//     asm queue stays homogeneous; then issues tiles 0,1.
// Geometry = R21 (proven clean): 625 x 512, 8 waves x 2 M-tiles, zero LDS,
// zero barriers, ~105 VGPR (fits the de-facto 128 arch-VGPR budget).
// MFMA 16x16x32 layouts (guide §3, m89/m91-verified):
//   A: lane l holds A[m0 + (l&15)][ks*32 + (l>>4)*8 + e]
//   B: lane l holds B[ks*32 + (l>>4)*8 + e][j0 + (l&15)]  (= featb[j][k])
//   D: lane l reg r = sim[m0 + (l>>4)*4 + r][j0 + (l&15)]
// ============================================================================
__global__ __launch_bounds__(512, 2) void triplet_main(
    const __bf16* __restrict__ inb, const __bf16* __restrict__ featb,
    const int* __restrict__ targets, const int* __restrict__ flabels,
    const int* __restrict__ idx,
    float* __restrict__ ppos, float* __restrict__ pneg)
{
  const int tid   = threadIdx.x;
  const int lane  = tid & 63;
  const int wv    = tid >> 6;       // 0..7: wave owns batch rows [32wv,32wv+32)
  const int l15   = lane & 15;
  const int lg    = lane >> 4;      // 0..3
  const int chunk = blockIdx.x;     // 0..624
  const int m0    = wv * 32;
  const int frow0 = chunk * CROWS;  // first of 160 feature rows

  // ---- prologue (normal loads): A fragments, meta
  bf8_t afrag[2][4];
#pragma unroll
  for (int mt = 0; mt < 2; ++mt) {
    const char* abase = (const char*)inb + (size_t)(m0 + mt * 16 + l15) * 256 + lg * 16;
#pragma unroll
    for (int ks = 0; ks < 4; ++ks)
      afrag[mt][ks] = *reinterpret_cast<const bf8_t*>(abase + ks * 64);
  }
  int meta[2][4];
#pragma unroll
  for (int mt = 0; mt < 2; ++mt)
#pragma unroll
    for (int rr = 0; rr < 4; ++rr) {
      const int row = m0 + mt * 16 + lg * 4 + rr;
      meta[mt][rr] = (idx[row] << 10) | targets[row];   // lab<1000: 10 bits
    }

  float minpos[2][4], maxneg[2][4];
#pragma unroll
  for (int mt = 0; mt < 2; ++mt)
#pragma unroll
    for (int rr = 0; rr < 4; ++rr) { minpos[mt][rr] = FLT_BIG; maxneg[mt][rr] = -FLT_BIG; }

  // ---- hand pipeline setup: SGPR bases + 32-bit per-lane voffsets
  const unsigned long long fb = (unsigned long long)featb;
  const unsigned long long fl = (unsigned long long)flabels;
  const unsigned voff0 = (unsigned)(frow0 + l15) * 256u + (unsigned)lg * 16u;
  const unsigned vlab0 = (unsigned)(frow0 + l15) * 4u;

#define SCHEDB()  __builtin_amdgcn_sched_barrier(0)
#define WAITVM(N) asm volatile("s_waitcnt vmcnt(" #N ")" ::: "memory")

  // tile t: 4 x 16B B-frag loads + 1 label load, all volatile asm
#define LOADT_ASM(buf, labv, t)                                               \
  do {                                                                        \
    unsigned vo_ = voff0 + (unsigned)(t) * 4096u;                             \
    unsigned vl_ = vlab0 + (unsigned)(t) * 64u;                               \
    asm volatile("global_load_dwordx4 %0, %1, %2 offset:0"                    \
                 : "=v"(buf[0]) : "v"(vo_), "s"(fb));                         \
    asm volatile("global_load_dwordx4 %0, %1, %2 offset:64"                   \
                 : "=v"(buf[1]) : "v"(vo_), "s"(fb));                         \
    asm volatile("global_load_dwordx4 %0, %1, %2 offset:128"                  \
                 : "=v"(buf[2]) : "v"(vo_), "s"(fb));                         \
    asm volatile("global_load_dwordx4 %0, %1, %2 offset:192"                  \
                 : "=v"(buf[3]) : "v"(vo_), "s"(fb));                         \
    asm volatile("global_load_dword %0, %1, %2 offset:0"                      \
                 : "=v"(labv) : "v"(vl_), "s"(fl));                           \
  } while (0)

#define TILE_COMPUTE(buf, labj, t)                                 \
  do {                                                             \
    f32x4 acc0 = {0.f, 0.f, 0.f, 0.f};                             \
    f32x4 acc1 = {0.f, 0.f, 0.f, 0.f};                             \
    _Pragma("unroll")                                              \
    for (int ks = 0; ks < 4; ++ks) {                               \
      acc0 = mfma_bf16(afrag[0][ks], buf[ks], acc0);               \
      acc1 = mfma_bf16(afrag[1][ks], buf[ks], acc1);               \
    }                                                              \
    const int j_ = frow0 + (t) * 16 + l15;                         \
    _Pragma("unroll")                                              \
    for (int rr = 0; rr < 4; ++rr) {                               \
      {                                                            \
        const int  m_   = meta[0][rr];                             \
        const bool same = ((labj) == (m_ & 1023));                 \
        const bool self = (j_ == (m_ >> 10));                      \
        minpos[0][rr] = fminf(minpos[0][rr],                       \
                              (same && !self) ? acc0[rr] : FLT_BIG); \
        maxneg[0][rr] = fmaxf(maxneg[0][rr],                       \
                              same ? -FLT_BIG : acc0[rr]);         \
      }                                                            \
      {                                                            \
        const int  m_   = meta[1][rr];                             \
        const bool same = ((labj) == (m_ & 1023));                 \
        const bool self = (j_ == (m_ >> 10));                      \
        minpos[1][rr] = fminf(minpos[1][rr],                       \
                              (same && !self) ? acc1[rr] : FLT_BIG); \
        maxneg[1][rr] = fmaxf(maxneg[1][rr],                       \
                              same ? -FLT_BIG : acc1[rr]);         \
      }                                                            \
    }                                                              \
  } while (0)

  // drain all prologue (normal) loads so the vmcnt queue holds ONLY our asm
  // loads; sched_barriers pin the boundary on both sides.
  SCHEDB(); WAITVM(0); SCHEDB();

  bf8_t bA[4], bB[4];
  int   labA, labB;
  LOADT_ASM(bA, labA, 0);
  LOADT_ASM(bB, labB, 1);

  // ---- main loop: wait vmcnt(5) (one tile outstanding) -> compute -> issue
#pragma unroll
  for (int t = 0; t < NTILE; t += 2) {
    {  // even tile t (bA)
      WAITVM(5); SCHEDB();
      const int labj = labA;
      TILE_COMPUTE(bA, labj, t);
      if (t + 2 < NTILE) LOADT_ASM(bA, labA, t + 2);
    }
    {  // odd tile t+1 (bB)
      if (t + 1 < NTILE - 1) { WAITVM(5); } else { WAITVM(0); }
      SCHEDB();
      const int labj = labB;
      TILE_COMPUTE(bB, labj, t + 1);
      if (t + 3 < NTILE) LOADT_ASM(bB, labB, t + 3);
    }
  }
#undef LOADT_ASM
#undef TILE_COMPUTE
#undef WAITVM
#undef SCHEDB

  // ---- reduce across the 16-lane col group; contiguous [chunk][row] write
#pragma unroll
  for (int mt = 0; mt < 2; ++mt)
#pragma unroll
    for (int rr = 0; rr < 4; ++rr) {
      float mp = minpos[mt][rr], mn = maxneg[mt][rr];
#pragma unroll
      for (int m = 1; m < 16; m <<= 1) {
        mp = fminf(mp, __shfl_xor(mp, m, 64));
        mn = fmaxf(mn, __shfl_xor(mn, m, 64));
      }
      if (l15 == 0) {
        const int row = m0 + mt * 16 + lg * 4 + rr;
        ppos[chunk * NBATCH + row] = mp;
        pneg[chunk * NBATCH + row] = mn;
      }
    }
}

// ============================================================================
// Fallback (ws too small): R13 f32 monolith, known-good ~43us path.
// ============================================================================
__global__ __launch_bounds__(512, 2) void triplet_partial_f32(
    const float* __restrict__ inputs, const float* __restrict__ features,
    const int* __restrict__ targets, const int* __restrict__ flabels,
    const int* __restrict__ idx,
    float* __restrict__ ppos, float* __restrict__ pneg,
    float* __restrict__ out)
{
  __shared__ char sB[RPBF * DIM * 4];

  const int tid  = threadIdx.x;
  const int lane = tid & 63;
  const int wv   = tid >> 6;
  const int l15  = lane & 15;
  const int lg   = lane >> 4;
  const int m0   = wv * 32;
  const int blk  = blockIdx.x;
  const int rowbase = blk * RPBF;

  if (blk == 0 && tid == 0) out[0] = 0.0f;

#pragma unroll
  for (int i = 0; i < NTILEF; ++i) {
    const int p    = i * 8192 + tid * 16;
    const int prow = p >> 9;
    const int scol = (p & 511) ^ ((prow & 7) << 4);
    stage16((const char*)features + (size_t)(rowbase + prow) * 512 + scol, &sB[p]);
  }

  bf8_t afrag[2][4];
#pragma unroll
  for (int mt = 0; mt < 2; ++mt) {
    const float* ap = inputs + (m0 + mt * 16 + l15) * DIM;
    float4 v0[4], v1[4];
#pragma unroll
    for (int ks = 0; ks < 4; ++ks) {
      const int k = ks * 32 + lg * 8;
      v0[ks] = *reinterpret_cast<const float4*>(ap + k);
      v1[ks] = *reinterpret_cast<const float4*>(ap + k + 4);
    }
#pragma unroll
    for (int ks = 0; ks < 4; ++ks)
      afrag[mt][ks] = pack8(v0[ks], v1[ks]);
  }

  int lab[NTILEF];
#pragma unroll
  for (int t = 0; t < NTILEF; ++t)
    lab[t] = flabels[rowbase + t * 16 + l15];

  int meta[2][4];
#pragma unroll
  for (int mt = 0; mt < 2; ++mt)
#pragma unroll
    for (int rr = 0; rr < 4; ++rr) {
      const int row = m0 + mt * 16 + lg * 4 + rr;
      meta[mt][rr] = (idx[row] << 10) | targets[row];
    }

  float minpos[2][4], maxneg[2][4];
#pragma unroll
  for (int mt = 0; mt < 2; ++mt)
#pragma unroll
    for (int rr = 0; rr < 4; ++rr) { minpos[mt][rr] = FLT_BIG; maxneg[mt][rr] = -FLT_BIG; }

  __syncthreads();

  const int swz = (l15 & 7) << 4;
#pragma unroll
  for (int t = 0; t < NTILEF; ++t) {
    const char* rbase = &sB[(t * 16 + l15) * 512];
    const int   j     = rowbase + t * 16 + l15;
    const int   labj  = lab[t];

    f32x4 acc0 = {0.f, 0.f, 0.f, 0.f};
    f32x4 acc1 = {0.f, 0.f, 0.f, 0.f};
#pragma unroll
    for (int ks = 0; ks < 4; ++ks) {
      const int o = ks * 128 + lg * 32;
      float4 v0 = *reinterpret_cast<const float4*>(rbase + ((o)      ^ swz));
      float4 v1 = *reinterpret_cast<const float4*>(rbase + ((o + 16) ^ swz));
      bf8_t bf = pack8(v0, v1);
      acc0 = mfma_bf16(afrag[0][ks], bf, acc0);
      acc1 = mfma_bf16(afrag[1][ks], bf, acc1);
    }
#pragma unroll
    for (int rr = 0; rr < 4; ++rr) {
      {
        const int  m = meta[0][rr];
        const bool same = (labj == (m & 1023));
        const bool self = (j == (m >> 10));
        minpos[0][rr] = fminf(minpos[0][rr], (same && !self) ? acc0[rr] : FLT_BIG);
        maxneg[0][rr] = fmaxf(maxneg[0][rr], same ? -FLT_BIG : acc0[rr]);
      }
      {
        const int  m = meta[1][rr];
        const bool same = (labj == (m & 1023));
        const bool self = (j == (m >> 10));
        minpos[1][rr] = fminf(minpos[1][rr], (same && !self) ? acc1[rr] : FLT_BIG);
        maxneg[1][rr] = fmaxf(maxneg[1][rr], same ? -FLT_BIG : acc1[rr]);
      }
    }
  }

#pragma unroll
  for (int mt = 0; mt < 2; ++mt)
#pragma unroll
    for (int rr = 0; rr < 4; ++rr) {
      float mp = minpos[mt][rr], mn = maxneg[mt][rr];
#pragma unroll
      for (int m = 1; m < 16; m <<= 1) {
        mp = fminf(mp, __shfl_xor(mp, m, 64));
        mn = fmaxf(mn, __shfl_xor(mn, m, 64));
      }
      if (l15 == 0) {
        const int row = m0 + mt * 16 + lg * 4 + rr;
        ppos[blk * NBATCH + row] = mp;
        pneg[blk * NBATCH + row] = mn;
      }
    }
}

// Kernel 2: one block per batch row; fold nblk partials, hinge, atomic mean.
__global__ __launch_bounds__(256) void triplet_reduce(
    const float* __restrict__ ppos, const float* __restrict__ pneg,
    float* __restrict__ out, int nblk)
{
  const int r = blockIdx.x;
  const int t = threadIdx.x;
  float mp = FLT_BIG, mn = -FLT_BIG;
  for (int b = t; b < nblk; b += 256) {
    mp = fminf(mp, ppos[b * NBATCH + r]);
    mn = fmaxf(mn, pneg[b * NBATCH + r]);
  }
#pragma unroll
  for (int m = 1; m < 64; m <<= 1) {
    mp = fminf(mp, __shfl_xor(mp, m, 64));
    mn = fmaxf(mn, __shfl_xor(mn, m, 64));
  }
  __shared__ float smp[4], smn[4];
  if ((t & 63) == 0) { smp[t >> 6] = mp; smn[t >> 6] = mn; }
  __syncthreads();
  if (t == 0) {
    mp = fminf(fminf(smp[0], smp[1]), fminf(smp[2], smp[3]));
    mn = fmaxf(fmaxf(smn[0], smn[1]), fmaxf(smn[2], smn[3]));
    float loss = mn - mp + MARGIN_F;
    loss = loss > 0.f ? loss : 0.f;
    atomicAdd(out, loss * (1.0f / NBATCH));
  }
}

extern "C" void kernel_launch(void* const* d_in, const int* in_sizes, int n_in,
                              void* d_out, int out_size, void* d_ws, size_t ws_size,
                              hipStream_t stream) {
  const float* inputs   = (const float*)d_in[0];
  const float* features = (const float*)d_in[1];
  const int*   targets  = (const int*)d_in[2];
  const int*   flabels  = (const int*)d_in[3];
  const int*   idx      = (const int*)d_in[4];
  float* out = (float*)d_out;

  const size_t featb_bytes = (size_t)NFEAT * DIM * 2;      // 25.6 MB
  const size_t inb_bytes   = (size_t)NBATCH * DIM * 2;     // 64 KB
  const size_t part_bytes  = (size_t)NCHUNK * NBATCH * 4;  // 640 KB each

  if (ws_size >= featb_bytes + inb_bytes + 2 * part_bytes) {
    __bf16* featb = (__bf16*)d_ws;
    __bf16* inb   = (__bf16*)((char*)d_ws + featb_bytes);
    float*  ppos  = (float*)((char*)d_ws + featb_bytes + inb_bytes);
    float*  pneg  = ppos + (size_t)NCHUNK * NBATCH;
    cast_bf16<<<2048, 256, 0, stream>>>(inputs, features, inb, featb, out);
    triplet_main<<<GRID, 512, 0, stream>>>(inb, featb, targets, flabels, idx, ppos, pneg);
    triplet_reduce<<<NBATCH, 256, 0, stream>>>(ppos, pneg, out, NCHUNK);
  } else {
    float* ppos = (float*)d_ws;                       // [GRIDF][256]
    float* pneg = ppos + (size_t)GRIDF * NBATCH;      // ~2.56 MB total
    triplet_partial_f32<<<GRIDF, 512, 0, stream>>>(inputs, features, targets,
                                                   flabels, idx, ppos, pneg, out);
    triplet_reduce<<<NBATCH, 256, 0, stream>>>(ppos, pneg, out, GRIDF);
  }
}

// Round 23
// 49.017 us; speedup vs baseline: 1.3846x; 1.3835x over previous
//
#include <hip/hip_runtime.h>

#define NFEAT   100000
#define NBATCH  256
#define DIM     128
#define MARGIN_F 0.5f
#define FLT_BIG 3.402823466e+38f

// ---- main geometry: 625 blocks x 160 feature rows = 100000 exactly
#define NCHUNK  625
#define CROWS   160
#define NTILE   10                 // 16-row B-tiles per block
#define GRID    NCHUNK
#define NTILES_ALL (NFEAT / 16)    // 6250 fragment-ordered tiles

// ---- f32 fallback geometry (R13): 1250 x 80
#define GRIDF   1250
#define RPBF    80
#define NTILEF  5

typedef __bf16 bf8_t  __attribute__((ext_vector_type(8)));
typedef short  sh8_t  __attribute__((ext_vector_type(8)));
typedef float  f32x4  __attribute__((ext_vector_type(4)));

__device__ __forceinline__ bf8_t pack8(float4 v0, float4 v1) {
  bf8_t r;
  r[0] = (__bf16)v0.x; r[1] = (__bf16)v0.y; r[2] = (__bf16)v0.z; r[3] = (__bf16)v0.w;
  r[4] = (__bf16)v1.x; r[5] = (__bf16)v1.y; r[6] = (__bf16)v1.z; r[7] = (__bf16)v1.w;
  return r;
}

template <typename VA, typename VC>
__device__ __forceinline__ auto mfma_sel(VA a, VA b, VC c, int)
    -> decltype(__builtin_amdgcn_mfma_f32_16x16x32_bf16(a, b, c, 0, 0, 0)) {
  return __builtin_amdgcn_mfma_f32_16x16x32_bf16(a, b, c, 0, 0, 0);
}
template <typename VA, typename VC>
__device__ __forceinline__ VC mfma_sel(VA a, VA b, VC c, long) {
  return __builtin_amdgcn_mfma_f32_16x16x32_bf16(
      __builtin_bit_cast(sh8_t, a), __builtin_bit_cast(sh8_t, b), c, 0, 0, 0);
}
__device__ __forceinline__ f32x4 mfma_bf16(bf8_t a, bf8_t b, f32x4 c) {
  return mfma_sel(a, b, c, 0);
}

#if defined(__has_builtin)
#if __has_builtin(__builtin_amdgcn_global_load_lds)
#define HAVE_GLLDS 1
#endif
#endif

__device__ __forceinline__ void stage16(const char* g, char* l) {
#ifdef HAVE_GLLDS
  __builtin_amdgcn_global_load_lds(
      (const __attribute__((address_space(1))) unsigned int*)g,
      (__attribute__((address_space(3))) unsigned int*)l, 16, 0, 0);
#else
  *reinterpret_cast<float4*>(l) = *reinterpret_cast<const float4*>(g);
#endif
}

// ============================================================================
// K1a (R23): cast f32->bf16 AND re-arrange features into MFMA FRAGMENT ORDER.
//   featbX byte offset(t, ks, lane) = t*4096 + ks*1024 + lane*16,
//   holding featb[t*16 + (lane&15)][ks*32 + (lane>>4)*8 .. +8].
// Why: R22 proved the GEMM's B-loads are throughput-bound, not latency-bound
// (hand-asm counted-vmcnt pipeline changed nothing). The old per-row loads
// were a GATHER -- one wave instruction touched 16 distinct 256B-strided
// cache lines (~16 TA line-transactions) vs K1a's 4 contiguous (9 TB/s
// shape). Fragment order makes every B-load 64 lanes x 16B CONTIGUOUS.
// inb stays row-major (A is prologue-only). Writes here are thread-contiguous;
// reads gather 16 rows x 32B per wave -- K1a has 6x headroom for that.
// ============================================================================
#define NG_IN   (NBATCH * DIM / 8)
#define NG_ALL  (NG_IN + NFEAT * DIM / 8)
__global__ __launch_bounds__(256) void cast_bf16(
    const float* __restrict__ inputs, const float* __restrict__ features,
    __bf16* __restrict__ inb, __bf16* __restrict__ featbX,
    float* __restrict__ out)
{
  if (blockIdx.x == 0 && threadIdx.x == 0) out[0] = 0.0f;  // K2 accumulates
  const int gid    = blockIdx.x * 256 + threadIdx.x;
  const int stride = gridDim.x * 256;
  for (int i = gid; i < NG_ALL; i += stride) {
    const float* src; __bf16* dst;
    if (i < NG_IN) {
      src = inputs + (size_t)i * 8;
      dst = inb + (size_t)i * 8;
    } else {
      const int g    = i - NG_IN;          // fragment-group id
      const int lane = g & 63;
      const int ks   = (g >> 6) & 3;
      const int t    = g >> 8;             // 0..6249
      src = features + ((size_t)(t * 16 + (lane & 15)) * DIM
                        + ks * 32 + (lane >> 4) * 8);
      dst = featbX + (size_t)g * 8;        // contiguous in g
    }
    float4 v0 = *reinterpret_cast<const float4*>(src);
    float4 v1 = *reinterpret_cast<const float4*>(src + 4);
    *reinterpret_cast<bf8_t*>(dst) = pack8(v0, v1);
  }
}

// ============================================================================
// K1b (R23): R22's hand-asm counted-vmcnt pipeline + FRAGMENT-ORDERED B.
// Every B-load is now 64x16B contiguous (4 cache lines/instruction, the only
// measured-fast load shape). All 8 waves of a block read the same 4KB tile ->
// 7/8 L1 hits on contiguous lines. Volatile-asm loads + s_waitcnt vmcnt(5)
// + sched_barrier(0): the schedule cannot be sunk/spilled/drained (R1-R21
// post-mortems: the prefetch never survived compilation by any other means).
// Geometry: 625 x 512 (8 waves x 2 M-tiles), zero LDS, zero barriers,
// ~88 VGPR (fits the de-facto 128 arch-VGPR budget, no spills R21-verified).
// MFMA 16x16x32 layouts (guide §3, m89/m91-verified):
//   A: lane l holds A[m0 + (l&15)][ks*32 + (l>>4)*8 + e]   (inb row-major)
//   B: lane l holds B[ks*32 + (l>>4)*8 + e][j0 + (l&15)]   (featbX frag-order)
//   D: lane l reg r = sim[m0 + (l>>4)*4 + r][j0 + (l&15)]
// ============================================================================
__global__ __launch_bounds__(512, 2) void triplet_main(
    const __bf16* __restrict__ inb, const __bf16* __restrict__ featbX,
    const int* __restrict__ targets, const int* __restrict__ flabels,
    const int* __restrict__ idx,
    float* __restrict__ ppos, float* __restrict__ pneg)
{
  const int tid   = threadIdx.x;
  const int lane  = tid & 63;
  const int wv    = tid >> 6;       // 0..7: wave owns batch rows [32wv,32wv+32)
  const int l15   = lane & 15;
  const int lg    = lane >> 4;      // 0..3
  const int chunk = blockIdx.x;     // 0..624
  const int m0    = wv * 32;
  const int frow0 = chunk * CROWS;  // first of 160 feature rows
  const int tile0 = chunk * NTILE;  // first fragment-tile index

  // ---- prologue (normal loads): A fragments, meta
  bf8_t afrag[2][4];
#pragma unroll
  for (int mt = 0; mt < 2; ++mt) {
    const char* abase = (const char*)inb + (size_t)(m0 + mt * 16 + l15) * 256 + lg * 16;
#pragma unroll
    for (int ks = 0; ks < 4; ++ks)
      afrag[mt][ks] = *reinterpret_cast<const bf8_t*>(abase + ks * 64);
  }
  int meta[2][4];
#pragma unroll
  for (int mt = 0; mt < 2; ++mt)
#pragma unroll
    for (int rr = 0; rr < 4; ++rr) {
      const int row = m0 + mt * 16 + lg * 4 + rr;
      meta[mt][rr] = (idx[row] << 10) | targets[row];   // lab<1000: 10 bits
    }

  float minpos[2][4], maxneg[2][4];
#pragma unroll
  for (int mt = 0; mt < 2; ++mt)
#pragma unroll
    for (int rr = 0; rr < 4; ++rr) { minpos[mt][rr] = FLT_BIG; maxneg[mt][rr] = -FLT_BIG; }

  // ---- hand pipeline: SGPR bases + 32-bit voffsets (frag-order: contiguous)
  const unsigned long long fb = (unsigned long long)featbX;
  const unsigned long long fl = (unsigned long long)flabels;
  const unsigned vlane = (unsigned)lane * 16u;              // lane slot in tile
  const unsigned vlab0 = (unsigned)(frow0 + l15) * 4u;

#define SCHEDB()  __builtin_amdgcn_sched_barrier(0)
#define WAITVM(N) asm volatile("s_waitcnt vmcnt(" #N ")" ::: "memory")

  // tile t: 4 x 1KB contiguous B-frag loads + 1 label load, volatile asm
#define LOADT_ASM(buf, labv, t)                                               \
  do {                                                                        \
    unsigned vo_ = vlane + (unsigned)(tile0 + (t)) * 4096u;                   \
    unsigned vl_ = vlab0 + (unsigned)(t) * 64u;                               \
    asm volatile("global_load_dwordx4 %0, %1, %2 offset:0"                    \
                 : "=v"(buf[0]) : "v"(vo_), "s"(fb));                         \
    asm volatile("global_load_dwordx4 %0, %1, %2 offset:1024"                 \
                 : "=v"(buf[1]) : "v"(vo_), "s"(fb));                         \
    asm volatile("global_load_dwordx4 %0, %1, %2 offset:2048"                 \
                 : "=v"(buf[2]) : "v"(vo_), "s"(fb));                         \
    asm volatile("global_load_dwordx4 %0, %1, %2 offset:3072"                 \
                 : "=v"(buf[3]) : "v"(vo_), "s"(fb));                         \
    asm volatile("global_load_dword %0, %1, %2 offset:0"                      \
                 : "=v"(labv) : "v"(vl_), "s"(fl));                           \
  } while (0)

#define TILE_COMPUTE(buf, labj, t)                                 \
  do {                                                             \
    f32x4 acc0 = {0.f, 0.f, 0.f, 0.f};                             \
    f32x4 acc1 = {0.f, 0.f, 0.f, 0.f};                             \
    _Pragma("unroll")                                              \
    for (int ks = 0; ks < 4; ++ks) {                               \
      acc0 = mfma_bf16(afrag[0][ks], buf[ks], acc0);               \
      acc1 = mfma_bf16(afrag[1][ks], buf[ks], acc1);               \
    }                                                              \
    const int j_ = frow0 + (t) * 16 + l15;                         \
    _Pragma("unroll")                                              \
    for (int rr = 0; rr < 4; ++rr) {                               \
      {                                                            \
        const int  m_   = meta[0][rr];                             \
        const bool same = ((labj) == (m_ & 1023));                 \
        const bool self = (j_ == (m_ >> 10));                      \
        minpos[0][rr] = fminf(minpos[0][rr],                       \
                              (same && !self) ? acc0[rr] : FLT_BIG); \
        maxneg[0][rr] = fmaxf(maxneg[0][rr],                       \
                              same ? -FLT_BIG : acc0[rr]);         \
      }                                                            \
      {                                                            \
        const int  m_   = meta[1][rr];                             \
        const bool same = ((labj) == (m_ & 1023));                 \
        const bool self = (j_ == (m_ >> 10));                      \
        minpos[1][rr] = fminf(minpos[1][rr],                       \
                              (same && !self) ? acc1[rr] : FLT_BIG); \
        maxneg[1][rr] = fmaxf(maxneg[1][rr],                       \
                              same ? -FLT_BIG : acc1[rr]);         \
      }                                                            \
    }                                                              \
  } while (0)

  // drain prologue loads so the vmcnt queue holds ONLY our asm loads
  SCHEDB(); WAITVM(0); SCHEDB();

  bf8_t bA[4], bB[4];
  int   labA, labB;
  LOADT_ASM(bA, labA, 0);
  LOADT_ASM(bB, labB, 1);

  // ---- main loop: wait vmcnt(5) (one tile outstanding) -> compute -> issue
#pragma unroll
  for (int t = 0; t < NTILE; t += 2) {
    {  // even tile t (bA)
      WAITVM(5); SCHEDB();
      const int labj = labA;
      TILE_COMPUTE(bA, labj, t);
      if (t + 2 < NTILE) LOADT_ASM(bA, labA, t + 2);
    }
    {  // odd tile t+1 (bB)
      if (t + 1 < NTILE - 1) { WAITVM(5); } else { WAITVM(0); }
      SCHEDB();
      const int labj = labB;
      TILE_COMPUTE(bB, labj, t + 1);
      if (t + 3 < NTILE) LOADT_ASM(bB, labB, t + 3);
    }
  }
#undef LOADT_ASM
#undef TILE_COMPUTE
#undef WAITVM
#undef SCHEDB

  // ---- reduce across the 16-lane col group; contiguous [chunk][row] write
#pragma unroll
  for (int mt = 0; mt < 2; ++mt)
#pragma unroll
    for (int rr = 0; rr < 4; ++rr) {
      float mp = minpos[mt][rr], mn = maxneg[mt][rr];
#pragma unroll
      for (int m = 1; m < 16; m <<= 1) {
        mp = fminf(mp, __shfl_xor(mp, m, 64));
        mn = fmaxf(mn, __shfl_xor(mn, m, 64));
      }
      if (l15 == 0) {
        const int row = m0 + mt * 16 + lg * 4 + rr;
        ppos[chunk * NBATCH + row] = mp;
        pneg[chunk * NBATCH + row] = mn;
      }
    }
}

// ============================================================================
// Fallback (ws too small): R13 f32 monolith, known-good ~43us path.
// ============================================================================
__global__ __launch_bounds__(512, 2) void triplet_partial_f32(
    const float* __restrict__ inputs, const float* __restrict__ features,
    const int* __restrict__ targets, const int* __restrict__ flabels,
    const int* __restrict__ idx,
    float* __restrict__ ppos, float* __restrict__ pneg,
    float* __restrict__ out)
{
  __shared__ char sB[RPBF * DIM * 4];

  const int tid  = threadIdx.x;
  const int lane = tid & 63;
  const int wv   = tid >> 6;
  const int l15  = lane & 15;
  const int lg   = lane >> 4;
  const int m0   = wv * 32;
  const int blk  = blockIdx.x;
  const int rowbase = blk * RPBF;

  if (blk == 0 && tid == 0) out[0] = 0.0f;

#pragma unroll
  for (int i = 0; i < NTILEF; ++i) {
    const int p    = i * 8192 + tid * 16;
    const int prow = p >> 9;
    const int scol = (p & 511) ^ ((prow & 7) << 4);
    stage16((const char*)features + (size_t)(rowbase + prow) * 512 + scol, &sB[p]);
  }

  bf8_t afrag[2][4];
#pragma unroll
  for (int mt = 0; mt < 2; ++mt) {
    const float* ap = inputs + (m0 + mt * 16 + l15) * DIM;
    float4 v0[4], v1[4];
#pragma unroll
    for (int ks = 0; ks < 4; ++ks) {
      const int k = ks * 32 + lg * 8;
      v0[ks] = *reinterpret_cast<const float4*>(ap + k);
      v1[ks] = *reinterpret_cast<const float4*>(ap + k + 4);
    }
#pragma unroll
    for (int ks = 0; ks < 4; ++ks)
      afrag[mt][ks] = pack8(v0[ks], v1[ks]);
  }

  int lab[NTILEF];
#pragma unroll
  for (int t = 0; t < NTILEF; ++t)
    lab[t] = flabels[rowbase + t * 16 + l15];

  int meta[2][4];
#pragma unroll
  for (int mt = 0; mt < 2; ++mt)
#pragma unroll
    for (int rr = 0; rr < 4; ++rr) {
      const int row = m0 + mt * 16 + lg * 4 + rr;
      meta[mt][rr] = (idx[row] << 10) | targets[row];
    }

  float minpos[2][4], maxneg[2][4];
#pragma unroll
  for (int mt = 0; mt < 2; ++mt)
#pragma unroll
    for (int rr = 0; rr < 4; ++rr) { minpos[mt][rr] = FLT_BIG; maxneg[mt][rr] = -FLT_BIG; }

  __syncthreads();

  const int swz = (l15 & 7) << 4;
#pragma unroll
  for (int t = 0; t < NTILEF; ++t) {
    const char* rbase = &sB[(t * 16 + l15) * 512];
    const int   j     = rowbase + t * 16 + l15;
    const int   labj  = lab[t];

    f32x4 acc0 = {0.f, 0.f, 0.f, 0.f};
    f32x4 acc1 = {0.f, 0.f, 0.f, 0.f};
#pragma unroll
    for (int ks = 0; ks < 4; ++ks) {
      const int o = ks * 128 + lg * 32;
      float4 v0 = *reinterpret_cast<const float4*>(rbase + ((o)      ^ swz));
      float4 v1 = *reinterpret_cast<const float4*>(rbase + ((o + 16) ^ swz));
      bf8_t bf = pack8(v0, v1);
      acc0 = mfma_bf16(afrag[0][ks], bf, acc0);
      acc1 = mfma_bf16(afrag[1][ks], bf, acc1);
    }
#pragma unroll
    for (int rr = 0; rr < 4; ++rr) {
      {
        const int  m = meta[0][rr];
        const bool same = (labj == (m & 1023));
        const bool self = (j == (m >> 10));
        minpos[0][rr] = fminf(minpos[0][rr], (same && !self) ? acc0[rr] : FLT_BIG);
        maxneg[0][rr] = fmaxf(maxneg[0][rr], same ? -FLT_BIG : acc0[rr]);
      }
      {
        const int  m = meta[1][rr];
        const bool same = (labj == (m & 1023));
        const bool self = (j == (m >> 10));
        minpos[1][rr] = fminf(minpos[1][rr], (same && !self) ? acc1[rr] : FLT_BIG);
        maxneg[1][rr] = fmaxf(maxneg[1][rr], same ? -FLT_BIG : acc1[rr]);
      }
    }
  }

#pragma unroll
  for (int mt = 0; mt < 2; ++mt)
#pragma unroll
    for (int rr = 0; rr < 4; ++rr) {
      float mp = minpos[mt][rr], mn = maxneg[mt][rr];
#pragma unroll
      for (int m = 1; m < 16; m <<= 1) {
        mp = fminf(mp, __shfl_xor(mp, m, 64));
        mn = fmaxf(mn, __shfl_xor(mn, m, 64));
      }
      if (l15 == 0) {
        const int row = m0 + mt * 16 + lg * 4 + rr;
        ppos[blk * NBATCH + row] = mp;
        pneg[blk * NBATCH + row] = mn;
      }
    }
}

// Kernel 2: one block per batch row; fold nblk partials, hinge, atomic mean.
__global__ __launch_bounds__(256) void triplet_reduce(
    const float* __restrict__ ppos, const float* __restrict__ pneg,
    float* __restrict__ out, int nblk)
{
  const int r = blockIdx.x;
  const int t = threadIdx.x;
  float mp = FLT_BIG, mn = -FLT_BIG;
  for (int b = t; b < nblk; b += 256) {
    mp = fminf(mp, ppos[b * NBATCH + r]);
    mn = fmaxf(mn, pneg[b * NBATCH + r]);
  }
#pragma unroll
  for (int m = 1; m < 64; m <<= 1) {
    mp = fminf(mp, __shfl_xor(mp, m, 64));
    mn = fmaxf(mn, __shfl_xor(mn, m, 64));
  }
  __shared__ float smp[4], smn[4];
  if ((t & 63) == 0) { smp[t >> 6] = mp; smn[t >> 6] = mn; }
  __syncthreads();
  if (t == 0) {
    mp = fminf(fminf(smp[0], smp[1]), fminf(smp[2], smp[3]));
    mn = fmaxf(fmaxf(smn[0], smn[1]), fmaxf(smn[2], smn[3]));
    float loss = mn - mp + MARGIN_F;
    loss = loss > 0.f ? loss : 0.f;
    atomicAdd(out, loss * (1.0f / NBATCH));
  }
}

extern "C" void kernel_launch(void* const* d_in, const int* in_sizes, int n_in,
                              void* d_out, int out_size, void* d_ws, size_t ws_size,
                              hipStream_t stream) {
  const float* inputs   = (const float*)d_in[0];
  const float* features = (const float*)d_in[1];
  const int*   targets  = (const int*)d_in[2];
  const int*   flabels  = (const int*)d_in[3];
  const int*   idx      = (const int*)d_in[4];
  float* out = (float*)d_out;

  const size_t featb_bytes = (size_t)NFEAT * DIM * 2;      // 25.6 MB
  const size_t inb_bytes   = (size_t)NBATCH * DIM * 2;     // 64 KB
  const size_t part_bytes  = (size_t)NCHUNK * NBATCH * 4;  // 640 KB each

  if (ws_size >= featb_bytes + inb_bytes + 2 * part_bytes) {
    __bf16* featbX = (__bf16*)d_ws;
    __bf16* inb    = (__bf16*)((char*)d_ws + featb_bytes);
    float*  ppos   = (float*)((char*)d_ws + featb_bytes + inb_bytes);
    float*  pneg   = ppos + (size_t)NCHUNK * NBATCH;
    cast_bf16<<<2048, 256, 0, stream>>>(inputs, features, inb, featbX, out);
    triplet_main<<<GRID, 512, 0, stream>>>(inb, featbX, targets, flabels, idx, ppos, pneg);
    triplet_reduce<<<NBATCH, 256, 0, stream>>>(ppos, pneg, out, NCHUNK);
  } else {
    float* ppos = (float*)d_ws;                       // [GRIDF][256]
    float* pneg = ppos + (size_t)GRIDF * NBATCH;      // ~2.56 MB total
    triplet_partial_f32<<<GRIDF, 512, 0, stream>>>(inputs, features, targets,
                                                   flabels, idx, ppos, pneg, out);
    triplet_reduce<<<NBATCH, 256, 0, stream>>>(ppos, pneg, out, GRIDF);
  }
}